// Round 1
// baseline (922.574 us; speedup 1.0000x reference)
//
#include <hip/hip_runtime.h>
#include <hip/hip_bf16.h>
#include <math.h>

typedef __hip_bfloat16 bf16;
typedef __attribute__((ext_vector_type(8))) short short8;
typedef __attribute__((ext_vector_type(4))) float floatx4;

// Problem constants
// B=32, H=W=32, C=384, NH=12, HEAD=32, WS=8, SS=4, N=64, nW/img=16, windows=512
// tokens T = 32768, HIDDEN = 1536
static constexpr int TOK = 32768;
static constexpr int CDIM = 384;
static constexpr int HID = 1536;

__device__ __forceinline__ bf16 f2bf(float v) { return __float2bfloat16(v); }

__device__ __forceinline__ void unpack8(uint4 u, float* f) {
  f[0] = __uint_as_float(u.x << 16); f[1] = __uint_as_float(u.x & 0xffff0000u);
  f[2] = __uint_as_float(u.y << 16); f[3] = __uint_as_float(u.y & 0xffff0000u);
  f[4] = __uint_as_float(u.z << 16); f[5] = __uint_as_float(u.z & 0xffff0000u);
  f[6] = __uint_as_float(u.w << 16); f[7] = __uint_as_float(u.w & 0xffff0000u);
}

__device__ __forceinline__ unsigned short bf_bits(float a) {
  bf16 h = __float2bfloat16(a);
  unsigned short u;
  __builtin_memcpy(&u, &h, 2);
  return u;
}
__device__ __forceinline__ unsigned pack2(float a, float b) {
  return (unsigned)bf_bits(a) | ((unsigned)bf_bits(b) << 16);
}

// ---------------- weight fp32 -> bf16 transposed ----------------
// src [Kd][Nd] fp32 row-major -> dst [Nd][Kd] bf16 row-major
__global__ void k_convt(const float* __restrict__ src, bf16* __restrict__ dst,
                        int Kd, int Nd) {
  int tid = blockIdx.x * 256 + threadIdx.x;
  if (tid >= Kd * Nd) return;
  int k = tid / Nd, n = tid - k * Nd;
  dst[(size_t)n * Kd + k] = f2bf(src[tid]);
}

// ---------------- LN1 + shift + window partition ----------------
// out row wt = win*64 + ntok (window-token order), bf16
__global__ __launch_bounds__(64) void k_ln1(const float* __restrict__ x,
                                            const float* __restrict__ g,
                                            const float* __restrict__ b,
                                            bf16* __restrict__ out) {
  int wt = blockIdx.x;
  int lane = threadIdx.x;
  int win = wt >> 6, ntok = wt & 63;
  int bimg = win >> 4, wi = win & 15;
  int sh = (((wi >> 2) << 3) + (ntok >> 3) + 4) & 31;
  int sw = (((wi & 3) << 3) + (ntok & 7) + 4) & 31;
  const float* xr = x + ((size_t)bimg * 1024 + sh * 32 + sw) * CDIM;
  float v[6]; float s = 0.f, ss = 0.f;
#pragma unroll
  for (int j = 0; j < 6; ++j) {
    float t = xr[j * 64 + lane];
    v[j] = t; s += t; ss += t * t;
  }
#pragma unroll
  for (int off = 32; off > 0; off >>= 1) {
    s += __shfl_xor(s, off, 64);
    ss += __shfl_xor(ss, off, 64);
  }
  float mu = s * (1.f / 384.f);
  float var = ss * (1.f / 384.f) - mu * mu;
  float rs = rsqrtf(var + 1e-5f);
  bf16* orow = out + (size_t)wt * CDIM;
#pragma unroll
  for (int j = 0; j < 6; ++j) {
    int c = j * 64 + lane;
    orow[c] = f2bf((v[j] - mu) * rs * g[c] + b[c]);
  }
}

// ---------------- LN2 (normal token order) ----------------
__global__ __launch_bounds__(64) void k_ln2(const float* __restrict__ x1,
                                            const float* __restrict__ g,
                                            const float* __restrict__ b,
                                            bf16* __restrict__ out) {
  int t = blockIdx.x;
  int lane = threadIdx.x;
  const float* xr = x1 + (size_t)t * CDIM;
  float v[6]; float s = 0.f, ss = 0.f;
#pragma unroll
  for (int j = 0; j < 6; ++j) {
    float q = xr[j * 64 + lane];
    v[j] = q; s += q; ss += q * q;
  }
#pragma unroll
  for (int off = 32; off > 0; off >>= 1) {
    s += __shfl_xor(s, off, 64);
    ss += __shfl_xor(ss, off, 64);
  }
  float mu = s * (1.f / 384.f);
  float var = ss * (1.f / 384.f) - mu * mu;
  float rs = rsqrtf(var + 1e-5f);
  bf16* orow = out + (size_t)t * CDIM;
#pragma unroll
  for (int j = 0; j < 6; ++j) {
    int c = j * 64 + lane;
    orow[c] = f2bf((v[j] - mu) * rs * g[c] + b[c]);
  }
}

// ---------------- generic MFMA core: wave computes 32 rows x 64 cols ----------
// A [M][K] bf16 row-major, Bt [N][K] bf16 row-major (i.e., B transposed)
// mfma_f32_16x16x32_bf16: A frag elem j = A[m=lane&15][k0+(lane>>4)*8+j]
//                         B frag elem j = B[k0+(lane>>4)*8+j][n=lane&15] = Bt[n][...]
//                         D: col=lane&15, row=(lane>>4)*4+reg
template <int K>
__device__ __forceinline__ void gemm_core(const bf16* __restrict__ A,
                                          const bf16* __restrict__ Bt,
                                          int mbase, int nbase,
                                          floatx4 acc[2][4]) {
  const int lane = threadIdx.x & 63;
  const int q = lane >> 4, mr = lane & 15;
  const short* a0p = (const short*)(A + (size_t)(mbase + mr) * K) + q * 8;
  const short* a1p = a0p + 16 * K;
  const short* bp = (const short*)(Bt + (size_t)(nbase + mr) * K) + q * 8;
#pragma unroll 4
  for (int k0 = 0; k0 < K; k0 += 32) {
    short8 a0 = *(const short8*)(a0p + k0);
    short8 a1 = *(const short8*)(a1p + k0);
#pragma unroll
    for (int nt = 0; nt < 4; ++nt) {
      short8 bfr = *(const short8*)(bp + nt * 16 * K + k0);
      acc[0][nt] = __builtin_amdgcn_mfma_f32_16x16x32_bf16(a0, bfr, acc[0][nt], 0, 0, 0);
      acc[1][nt] = __builtin_amdgcn_mfma_f32_16x16x32_bf16(a1, bfr, acc[1][nt], 0, 0, 0);
    }
  }
}

#define GEMM_PROLOGUE(KVAL)                                   \
  int wave = threadIdx.x >> 6;                                \
  int mbase = blockIdx.x * 128 + wave * 32;                   \
  int nbase = blockIdx.y * 64;                                \
  floatx4 acc[2][4];                                          \
  _Pragma("unroll") for (int i = 0; i < 2; ++i)               \
      _Pragma("unroll") for (int j = 0; j < 4; ++j)           \
          acc[i][j] = floatx4{0.f, 0.f, 0.f, 0.f};            \
  gemm_core<KVAL>(A, Bt, mbase, nbase, acc);                  \
  int lane = threadIdx.x & 63;                                \
  int q = lane >> 4, mr = lane & 15;

// ---------------- QKV GEMM: out -> qkv[s][win][head][n][d] bf16 -------------
__global__ __launch_bounds__(256) void k_gemm_qkv(const bf16* __restrict__ A,
                                                  const bf16* __restrict__ Bt,
                                                  const float* __restrict__ bias,
                                                  bf16* __restrict__ out) {
  GEMM_PROLOGUE(384)
#pragma unroll
  for (int nt = 0; nt < 4; ++nt) {
    int col = nbase + nt * 16 + mr;
    int s = col / 384;
    int rem = col - s * 384;
    int h = rem >> 5, d = rem & 31;
    float bv = bias[col];
#pragma unroll
    for (int rt = 0; rt < 2; ++rt)
#pragma unroll
      for (int r = 0; r < 4; ++r) {
        int row = mbase + rt * 16 + q * 4 + r;
        int win = row >> 6, ntok = row & 63;
        out[((((size_t)s * 512 + win) * 12 + h) * 64 + ntok) * 32 + d] =
            f2bf(acc[rt][nt][r] + bv);
      }
  }
}

// ---------------- attention: 1 wave per (window, head) ----------------------
__global__ __launch_bounds__(64) void k_attn(const bf16* __restrict__ qkv,
                                             const float* __restrict__ tblg,
                                             bf16* __restrict__ out) {
  __shared__ __attribute__((aligned(16))) float ks[64][32];
  __shared__ __attribute__((aligned(16))) float vs[64][32];
  __shared__ float tbl[2700];
  __shared__ int rids[64];
  int bid = blockIdx.x;
  int win = bid / 12, head = bid - win * 12;
  int lane = threadIdx.x;
  for (int i = lane; i < 2700; i += 64) tbl[i] = tblg[i];

  size_t base = ((size_t)win * 12 + head) * 2048 + lane * 32;
  const uint4* qp = (const uint4*)(qkv + base);
  const uint4* kp = (const uint4*)(qkv + (size_t)12582912 + base);
  const uint4* vp = (const uint4*)(qkv + (size_t)25165824 + base);

  float qreg[32];
#pragma unroll
  for (int i = 0; i < 4; ++i) { uint4 u = qp[i]; unpack8(u, qreg + i * 8); }
#pragma unroll
  for (int i = 0; i < 4; ++i) {
    uint4 u = kp[i]; float f[8]; unpack8(u, f);
#pragma unroll
    for (int j = 0; j < 8; ++j) ks[lane][i * 8 + j] = f[j];
  }
#pragma unroll
  for (int i = 0; i < 4; ++i) {
    uint4 u = vp[i]; float f[8]; unpack8(u, f);
#pragma unroll
    for (int j = 0; j < 8; ++j) vs[lane][i * 8 + j] = f[j];
  }
  int wi = win & 15;
  int hb = (wi >> 2) << 3, wb = (wi & 3) << 3;
  int r_i = lane >> 3, c_i = lane & 7;
  int rh = hb + r_i, rw = wb + c_i;
  int rid = (rh < 24 ? 0 : (rh < 28 ? 1 : 2)) * 3 + (rw < 24 ? 0 : (rw < 28 ? 1 : 2));
  rids[lane] = rid;
  __syncthreads();

  float s[64];
  float mx = -1e30f;
#pragma unroll
  for (int j = 0; j < 64; ++j) {
    const float4* kr = (const float4*)ks[j];
    float dot = 0.f;
#pragma unroll
    for (int d4 = 0; d4 < 8; ++d4) {
      float4 kk = kr[d4];
      dot += qreg[d4 * 4 + 0] * kk.x;
      dot += qreg[d4 * 4 + 1] * kk.y;
      dot += qreg[d4 * 4 + 2] * kk.z;
      dot += qreg[d4 * 4 + 3] * kk.w;
    }
    int r_j = j >> 3, c_j = j & 7;
    float bias = tbl[((r_i - r_j + 7) * 15 + (c_i - c_j + 7)) * 12 + head];
    float val = dot * 0.17677669529663687f + bias + (rid == rids[j] ? 0.f : -100.f);
    s[j] = val;
    mx = fmaxf(mx, val);
  }
  float l = 0.f;
#pragma unroll
  for (int j = 0; j < 64; ++j) {
    float p = __expf(s[j] - mx);
    s[j] = p;
    l += p;
  }
  float inv = 1.f / l;
  float o[32];
#pragma unroll
  for (int d = 0; d < 32; ++d) o[d] = 0.f;
#pragma unroll
  for (int j = 0; j < 64; ++j) {
    float p = s[j];
    const float4* vr = (const float4*)vs[j];
#pragma unroll
    for (int d4 = 0; d4 < 8; ++d4) {
      float4 vv = vr[d4];
      o[d4 * 4 + 0] += p * vv.x;
      o[d4 * 4 + 1] += p * vv.y;
      o[d4 * 4 + 2] += p * vv.z;
      o[d4 * 4 + 3] += p * vv.w;
    }
  }
  uint4* o4 = (uint4*)(out + ((size_t)win * 64 + lane) * CDIM + head * 32);
#pragma unroll
  for (int i = 0; i < 4; ++i) {
    uint4 pk;
    pk.x = pack2(o[i * 8 + 0] * inv, o[i * 8 + 1] * inv);
    pk.y = pack2(o[i * 8 + 2] * inv, o[i * 8 + 3] * inv);
    pk.z = pack2(o[i * 8 + 4] * inv, o[i * 8 + 5] * inv);
    pk.w = pack2(o[i * 8 + 6] * inv, o[i * 8 + 7] * inv);
    o4[i] = pk;
  }
}

// ---------------- proj GEMM + window reverse + unshift + shortcut -----------
__global__ __launch_bounds__(256) void k_gemm_proj(const bf16* __restrict__ A,
                                                   const bf16* __restrict__ Bt,
                                                   const float* __restrict__ bias,
                                                   const float* __restrict__ xin,
                                                   float* __restrict__ x1) {
  GEMM_PROLOGUE(384)
#pragma unroll
  for (int nt = 0; nt < 4; ++nt) {
    int col = nbase + nt * 16 + mr;
    float bv = bias[col];
#pragma unroll
    for (int rt = 0; rt < 2; ++rt)
#pragma unroll
      for (int r = 0; r < 4; ++r) {
        int row = mbase + rt * 16 + q * 4 + r;
        int win = row >> 6, ntok = row & 63;
        int bimg = win >> 4, wi = win & 15;
        int hh = (((wi >> 2) << 3) + (ntok >> 3) + 4) & 31;
        int ww = (((wi & 3) << 3) + (ntok & 7) + 4) & 31;
        size_t t = (size_t)bimg * 1024 + hh * 32 + ww;
        x1[t * CDIM + col] = xin[t * CDIM + col] + acc[rt][nt][r] + bv;
      }
  }
}

// ---------------- FC1 GEMM + bias + GELU -> hidden bf16 ---------------------
__global__ __launch_bounds__(256) void k_gemm_fc1(const bf16* __restrict__ A,
                                                  const bf16* __restrict__ Bt,
                                                  const float* __restrict__ bias,
                                                  bf16* __restrict__ hidden) {
  GEMM_PROLOGUE(384)
#pragma unroll
  for (int nt = 0; nt < 4; ++nt) {
    int col = nbase + nt * 16 + mr;
    float bv = bias[col];
#pragma unroll
    for (int rt = 0; rt < 2; ++rt)
#pragma unroll
      for (int r = 0; r < 4; ++r) {
        int row = mbase + rt * 16 + q * 4 + r;
        float z = acc[rt][nt][r] + bv;
        float u = 0.7978845608028654f * (z + 0.044715f * z * z * z);
        float gv = 0.5f * z * (1.f + tanhf(u));
        hidden[(size_t)row * HID + col] = f2bf(gv);
      }
  }
}

// ---------------- FC2 GEMM + bias + residual -> out fp32 --------------------
__global__ __launch_bounds__(256) void k_gemm_fc2(const bf16* __restrict__ A,
                                                  const bf16* __restrict__ Bt,
                                                  const float* __restrict__ bias,
                                                  const float* __restrict__ x1,
                                                  float* __restrict__ out) {
  GEMM_PROLOGUE(1536)
#pragma unroll
  for (int nt = 0; nt < 4; ++nt) {
    int col = nbase + nt * 16 + mr;
    float bv = bias[col];
#pragma unroll
    for (int rt = 0; rt < 2; ++rt)
#pragma unroll
      for (int r = 0; r < 4; ++r) {
        int row = mbase + rt * 16 + q * 4 + r;
        out[(size_t)row * CDIM + col] = x1[(size_t)row * CDIM + col] + acc[rt][nt][r] + bv;
      }
  }
}

extern "C" void kernel_launch(void* const* d_in, const int* in_sizes, int n_in,
                              void* d_out, int out_size, void* d_ws, size_t ws_size,
                              hipStream_t stream) {
  const float* x = (const float*)d_in[0];
  const float* n1g = (const float*)d_in[1];
  const float* n1b = (const float*)d_in[2];
  const float* qkv_w = (const float*)d_in[3];
  const float* qkv_b = (const float*)d_in[4];
  const float* reltbl = (const float*)d_in[5];
  const float* proj_w = (const float*)d_in[6];
  const float* proj_b = (const float*)d_in[7];
  const float* n2g = (const float*)d_in[8];
  const float* n2b = (const float*)d_in[9];
  const float* fc1_w = (const float*)d_in[10];
  const float* fc1_b = (const float*)d_in[11];
  const float* fc2_w = (const float*)d_in[12];
  const float* fc2_b = (const float*)d_in[13];
  float* out = (float*)d_out;

  // workspace layout (~180 MB)
  char* p = (char*)d_ws;
  bf16* w_qkv_t = (bf16*)p;  p += (size_t)442368 * 2;    // [1152][384]
  bf16* w_proj_t = (bf16*)p; p += (size_t)147456 * 2;    // [384][384]
  bf16* w_fc1_t = (bf16*)p;  p += (size_t)589824 * 2;    // [1536][384]
  bf16* w_fc2_t = (bf16*)p;  p += (size_t)589824 * 2;    // [384][1536]
  bf16* bufA = (bf16*)p;     p += (size_t)12582912 * 2;  // [T][C] bf16 (LN out, reused)
  bf16* qkvb = (bf16*)p;     p += (size_t)37748736 * 2;  // [3][512][12][64][32] bf16
  bf16* attno = (bf16*)p;    p += (size_t)12582912 * 2;  // [T][C] bf16 (attn out)
  float* x1 = (float*)p;     p += (size_t)12582912 * 4;  // [T][C] fp32 (residual)
  bf16* hidden = qkvb;  // [T][1536] bf16, reuses qkvb+attno regions (both dead)

  // weights -> bf16 transposed
  k_convt<<<dim3((442368 + 255) / 256), dim3(256), 0, stream>>>(qkv_w, w_qkv_t, 384, 1152);
  k_convt<<<dim3((147456 + 255) / 256), dim3(256), 0, stream>>>(proj_w, w_proj_t, 384, 384);
  k_convt<<<dim3((589824 + 255) / 256), dim3(256), 0, stream>>>(fc1_w, w_fc1_t, 384, 1536);
  k_convt<<<dim3((589824 + 255) / 256), dim3(256), 0, stream>>>(fc2_w, w_fc2_t, 1536, 384);

  // LN1 + shift + window partition
  k_ln1<<<dim3(32768), dim3(64), 0, stream>>>(x, n1g, n1b, bufA);
  // QKV
  k_gemm_qkv<<<dim3(256, 18), dim3(256), 0, stream>>>(bufA, w_qkv_t, qkv_b, qkvb);
  // attention
  k_attn<<<dim3(6144), dim3(64), 0, stream>>>(qkvb, reltbl, attno);
  // proj + reverse + shortcut
  k_gemm_proj<<<dim3(256, 6), dim3(256), 0, stream>>>(attno, w_proj_t, proj_b, x, x1);
  // LN2
  k_ln2<<<dim3(32768), dim3(64), 0, stream>>>(x1, n2g, n2b, bufA);
  // FC1 + GELU
  k_gemm_fc1<<<dim3(256, 24), dim3(256), 0, stream>>>(bufA, w_fc1_t, fc1_b, hidden);
  // FC2 + residual
  k_gemm_fc2<<<dim3(256, 6), dim3(256), 0, stream>>>(hidden, w_fc2_t, fc2_b, x1, out);
}